// Round 2
// baseline (875.593 us; speedup 1.0000x reference)
//
#include <hip/hip_runtime.h>

// StabilityPredictorSchnet: B=4, L=384, H=128, F=384
// R2: prep pre-converts h_E -> bf16 AND pre-XOR-swizzles each 64x128 tile
// (unit u -> u^(row&7)) so a LINEAR global_load_lds lands conflict-free for
// MFMA A-fragment reads. Kills the fp32 stage + repack phase + 2 barriers/it.
// sT1 is linear [64][48 16B-units], same XOR swizzle (writes & reads agree).
// DMA of tile it+1 issues after the post-epi1 barrier, hides under GEMM2
// (single sA buffer; end-of-iter barrier's vmcnt drain publishes it).
// LDS 72->64 KB. R1 lesson: (512,4)=128 unified regs spilled 178MB with the
// repack live; with repack gone the GEMM working set (~110 regs) fits.

#define Bz 4
#define Lz 384
#define Hz 128
#define Fz 384
#define KT 64          // k-tile rows (edge rows per iteration)
#define NIT 6          // 384 / KT
#define TILE_B (KT * Hz * 2)   // 16384 B per bf16 tile

typedef short bf16x8 __attribute__((ext_vector_type(8)));
typedef float f32x4 __attribute__((ext_vector_type(4)));

__device__ __forceinline__ unsigned short f2bf(float f) {
  unsigned int u = __float_as_uint(f);
  u += 0x7FFFu + ((u >> 16) & 1u);   // RNE bf16
  return (unsigned short)(u >> 16);
}

// gelu(x) = 0.5x(1+erf(x/sqrt2)); erf via A&S 7.1.26 (|err|<=1.5e-7)
__device__ __forceinline__ float gelu_f(float x) {
  const float a1 = 0.254829592f, a2 = -0.284496736f, a3 = 1.421413741f;
  const float a4 = -1.453152027f, a5 = 1.061405429f;
  float z = fabsf(x) * 0.7071067811865476f;
  float t = __builtin_amdgcn_rcpf(__builtin_fmaf(0.3275911f, z, 1.0f));
  float poly = t * (a1 + t * (a2 + t * (a3 + t * (a4 + t * a5))));
  float e = __builtin_fmaf(-poly, __expf(-z * z), 1.0f);
  return 0.5f * x * (1.0f + copysignf(e, x));
}

// ---- prep: zero acc/ctr; pack fw1/fw2 (B-frag order); h_E -> bf16 tiles ----
// hEP unit q = ((bl*NIT+it)*64 + r)*16 + u  holds bf16 of
//   hE[bl][it*64+r][ (u^(r&7))*8 .. +8 )   (tile-local XOR pre-swizzle)
__global__ __launch_bounds__(256) void prep_kernel(
    const float* __restrict__ fw1, const float* __restrict__ fw2,
    const float* __restrict__ hE,
    unsigned short* __restrict__ fw1P, unsigned short* __restrict__ fw2P,
    unsigned short* __restrict__ hEP,
    float* __restrict__ accbuf, int* __restrict__ ctr)
{
  int e = blockIdx.x * 256 + threadIdx.x;
  if (e < 16) accbuf[e] = 0.0f;
  if (e == 16) *ctr = 0;
  if (e < 24 * 4 * 64 * 8) {
    int j = e & 7, lf = (e >> 3) & 63, ks = (e >> 9) & 3, t = e >> 11;
    int n = t * 16 + (lf & 15);
    int k = ks * 32 + (lf >> 4) * 8 + j;
    fw1P[e] = f2bf(fw1[(size_t)k * Fz + n]);
  } else if (e < 24 * 4 * 64 * 8 + 24 * 12 * 64 * 8) {
    int o = e - 24 * 4 * 64 * 8;
    int j = o & 7, lf = (o >> 3) & 63, r = o >> 9;
    int ks = r % 12, t = r / 12;
    int n = t * 16 + (lf & 15);
    int k = ks * 32 + (lf >> 4) * 8 + j;
    fw2P[o] = f2bf(fw2[(size_t)k * Fz + n]);
  }
  if (e < Bz * Lz * NIT * KT * 16) {
    int u = e & 15;
    int r = (e >> 4) & 63;
    int tile = e >> 10;                 // bl*NIT + it
    int it = tile % NIT;
    int bl = tile / NIT;
    const float* src = hE + (size_t)bl * (Lz * Hz)
                       + (size_t)(it * KT + r) * Hz + ((u ^ (r & 7)) << 3);
    f32x4 v0 = *(const f32x4*)src;
    f32x4 v1 = *(const f32x4*)(src + 4);
    bf16x8 o;
    o[0] = (short)f2bf(v0[0]); o[1] = (short)f2bf(v0[1]);
    o[2] = (short)f2bf(v0[2]); o[3] = (short)f2bf(v0[3]);
    o[4] = (short)f2bf(v1[0]); o[5] = (short)f2bf(v1[1]);
    o[6] = (short)f2bf(v1[2]); o[7] = (short)f2bf(v1[3]);
    *(bf16x8*)(hEP + (size_t)e * 8) = o;
  }
}

__global__ __launch_bounds__(512, 4) void schnet_main(
    const float* __restrict__ hV, const unsigned short* __restrict__ hEP,
    const float* __restrict__ mask,
    const unsigned short* __restrict__ fw1P, const float* __restrict__ fb1,
    const unsigned short* __restrict__ fw2P, const float* __restrict__ fb2,
    const float* __restrict__ hw1, const float* __restrict__ hb1,
    const float* __restrict__ hw2, const float* __restrict__ hb2,
    const float* __restrict__ hw3, const float* __restrict__ hb3,
    float* __restrict__ accbuf, int* __restrict__ ctr,
    float* __restrict__ out)
{
  const int bl   = blockIdx.x;
  const int b    = bl / Lz;
  const int l    = bl - b * Lz;
  const int tid  = threadIdx.x;
  const int wave = tid >> 6;    // 0..7
  const int lane = tid & 63;
  const int lr   = lane & 15;
  const int quad = lane >> 4;   // 0..3
  const int l7   = lane & 7;

  // 64 KB: sA bf16 swizzled tile @0 (16K), sT1 swizzled @16K (48K).
  // Head-MLP buffers alias the sA region after the main loop.
  __shared__ __attribute__((aligned(16))) char sMem[65536];
  unsigned short* sA  = (unsigned short*)sMem;             // [64][16 units]
  unsigned short* sT1 = (unsigned short*)(sMem + 16384);   // [64][48 units]
  float* sXC = (float*)sMem;           // 384 f
  float* sHp = sXC + Fz;               // 4*128 f
  float* sH1 = sHp + 4 * Hz;           // 128 f
  float* sH2 = sH1 + Hz;               // 64 f
  int*   sLast = (int*)(sH2 + 64);

  const char* hEPt = (const char*)hEP + (size_t)bl * (NIT * TILE_B);
  const unsigned short* w1base = fw1P + (size_t)lane * 8;
  const unsigned short* w2base = fw2P + (size_t)lane * 8;

  const f32x4 zero4 = {0.f, 0.f, 0.f, 0.f};
  f32x4 xc[3];
  xc[0] = zero4; xc[1] = zero4; xc[2] = zero4;

  // prologue: DMA tile 0 -> sA (linear; data pre-swizzled by prep)
  #pragma unroll
  for (int j = 0; j < 2; ++j) {
    int off = (j * 8 + wave) << 10;
    __builtin_amdgcn_global_load_lds(
        (const __attribute__((address_space(1))) void*)(hEPt + off + lane * 16),
        (__attribute__((address_space(3))) void*)(sMem + off), 16, 0, 0);
  }
  __syncthreads();   // implicit vmcnt drain -> sA ready

  for (int it = 0; it < NIT; ++it) {
    // ===== GEMM1 (swapped mfma -> C^T): wave owns 48 cols =====
    {
      f32x4 acc[4][3];
      #pragma unroll
      for (int mt = 0; mt < 4; ++mt)
        #pragma unroll
        for (int nt = 0; nt < 3; ++nt) acc[mt][nt] = zero4;

      #pragma unroll 2
      for (int ks = 0; ks < 4; ++ks) {
        const int xu = ((ks << 2) + quad) ^ l7;   // swizzled 16B-unit
        bf16x8 afr[4];
        #pragma unroll
        for (int mt = 0; mt < 4; ++mt)
          afr[mt] = *(const bf16x8*)(sA + ((mt * 16 + lr) << 7) + (xu << 3));
        bf16x8 bfr[3];
        #pragma unroll
        for (int nt = 0; nt < 3; ++nt)
          bfr[nt] = *(const bf16x8*)(w1base +
                        (size_t)(((wave * 3 + nt) * 4 + ks) * 64) * 8);
        __builtin_amdgcn_s_setprio(1);
        #pragma unroll
        for (int mt = 0; mt < 4; ++mt)
          #pragma unroll
          for (int nt = 0; nt < 3; ++nt)
            acc[mt][nt] = __builtin_amdgcn_mfma_f32_16x16x32_bf16(
                bfr[nt], afr[mt], acc[mt][nt], 0, 0, 0);
        __builtin_amdgcn_s_setprio(0);
      }
      // epi1: bias+gelu -> sT1 (swizzled write; lane holds 4 consecutive n)
      #pragma unroll
      for (int nt = 0; nt < 3; ++nt) {
        const int n0 = wave * 48 + nt * 16 + quad * 4;
        const f32x4 bias = *(const f32x4*)(fb1 + n0);
        const int so = (((wave * 6 + nt * 2 + (quad >> 1)) ^ l7) << 3)
                       + ((quad & 1) << 2);
        #pragma unroll
        for (int mt = 0; mt < 4; ++mt) {
          short4 o;
          o.x = (short)f2bf(gelu_f(acc[mt][nt][0] + bias[0]));
          o.y = (short)f2bf(gelu_f(acc[mt][nt][1] + bias[1]));
          o.z = (short)f2bf(gelu_f(acc[mt][nt][2] + bias[2]));
          o.w = (short)f2bf(gelu_f(acc[mt][nt][3] + bias[3]));
          *(short4*)(sT1 + (mt * 16 + lr) * 384 + so) = o;
        }
      }
    }
    __syncthreads();   // sT1 ready; all sA reads complete

    // DMA next tile -> sA; hides under GEMM2, published by end-of-iter drain
    if (it + 1 < NIT) {
      const char* gt = hEPt + (it + 1) * TILE_B;
      #pragma unroll
      for (int j = 0; j < 2; ++j) {
        int off = (j * 8 + wave) << 10;
        __builtin_amdgcn_global_load_lds(
            (const __attribute__((address_space(1))) void*)(gt + off + lane * 16),
            (__attribute__((address_space(3))) void*)(sMem + off), 16, 0, 0);
      }
    }

    // ===== GEMM2 (swapped mfma -> C^T) =====
    {
      f32x4 acc[4][3];
      #pragma unroll
      for (int mt = 0; mt < 4; ++mt)
        #pragma unroll
        for (int nt = 0; nt < 3; ++nt) acc[mt][nt] = zero4;

      #pragma unroll 2
      for (int ks = 0; ks < 12; ++ks) {
        const int xu = ((ks << 2) + quad) ^ l7;
        bf16x8 afr[4];
        #pragma unroll
        for (int mt = 0; mt < 4; ++mt)
          afr[mt] = *(const bf16x8*)(sT1 + (mt * 16 + lr) * 384 + (xu << 3));
        bf16x8 bfr[3];
        #pragma unroll
        for (int nt = 0; nt < 3; ++nt)
          bfr[nt] = *(const bf16x8*)(w2base +
                        (size_t)(((wave * 3 + nt) * 12 + ks) * 64) * 8);
        __builtin_amdgcn_s_setprio(1);
        #pragma unroll
        for (int mt = 0; mt < 4; ++mt)
          #pragma unroll
          for (int nt = 0; nt < 3; ++nt)
            acc[mt][nt] = __builtin_amdgcn_mfma_f32_16x16x32_bf16(
                bfr[nt], afr[mt], acc[mt][nt], 0, 0, 0);
        __builtin_amdgcn_s_setprio(0);
      }
      // epi2: bias+gelu, * h_V[b, k=m, n] (float4), accumulate per n
      #pragma unroll
      for (int nt = 0; nt < 3; ++nt) {
        const int n0 = wave * 48 + nt * 16 + quad * 4;
        const f32x4 b2 = *(const f32x4*)(fb2 + n0);
        #pragma unroll
        for (int mt = 0; mt < 4; ++mt) {
          const float* hv =
              hV + ((size_t)b * Lz + it * KT + mt * 16 + lr) * Fz + n0;
          const f32x4 hvv = *(const f32x4*)hv;
          #pragma unroll
          for (int r = 0; r < 4; ++r)
            xc[nt][r] += gelu_f(acc[mt][nt][r] + b2[r]) * hvv[r];
        }
      }
    }
    __syncthreads();   // sT1 free for next epi1; vmcnt drained -> sA ready
  }

  // reduce xc across the 16 lr lanes -> sXC[n] (aliases sA region, loop done)
  #pragma unroll
  for (int nt = 0; nt < 3; ++nt)
    #pragma unroll
    for (int r = 0; r < 4; ++r) {
      float v = xc[nt][r];
      v += __shfl_xor(v, 1);
      v += __shfl_xor(v, 2);
      v += __shfl_xor(v, 4);
      v += __shfl_xor(v, 8);
      if (lr == 0) sXC[wave * 48 + nt * 16 + quad * 4 + r] = v;
    }
  __syncthreads();

  // ---- head MLP (fp32, tiny) ----
  {
    int i = tid & 127;
    int part = tid >> 7;              // 0..3
    float a = 0.f;
    const int f0 = part * 96;
    for (int f = f0; f < f0 + 96; ++f) a += sXC[f] * hw1[f * Hz + i];
    sHp[part * Hz + i] = a;
  }
  __syncthreads();
  if (tid < Hz)
    sH1[tid] = gelu_f(sHp[tid] + sHp[Hz + tid] + sHp[2 * Hz + tid]
                      + sHp[3 * Hz + tid] + hb1[tid]);
  __syncthreads();
  if (tid < 64) {
    float a = hb2[tid];
    for (int i = 0; i < Hz; ++i) a += sH1[i] * hw2[i * 64 + tid];
    sH2[tid] = gelu_f(a);
  }
  __syncthreads();
  if (wave == 0) {
    float v = sH2[lane] * hw3[lane];
    #pragma unroll
    for (int off = 32; off >= 1; off >>= 1) v += __shfl_xor(v, off);
    if (lane == 0) {
      float pred = v + hb3[0];
      atomicAdd(&accbuf[b], pred * mask[b * Lz + l]);
      __threadfence();
      *sLast = (atomicAdd(ctr, 1) == (Bz * Lz - 1));
    }
  }
  __syncthreads();

  // ---- last block: finalize all 4 batches ----
  if (*sLast && wave < Bz) {
    float s = 0.f;
    #pragma unroll
    for (int k = 0; k < Lz / 64; ++k) s += mask[wave * Lz + k * 64 + lane];
    #pragma unroll
    for (int off = 32; off >= 1; off >>= 1) s += __shfl_xor(s, off);
    if (lane == 0) {
      float vl = s < 1.0f ? 1.0f : s;
      float a = atomicAdd(&accbuf[wave], 0.0f);   // coherent read
      out[wave] = a / sqrtf(vl);
    }
  }
}

extern "C" void kernel_launch(void* const* d_in, const int* in_sizes, int n_in,
                              void* d_out, int out_size, void* d_ws, size_t ws_size,
                              hipStream_t stream)
{
  const float* hV   = (const float*)d_in[0];
  const float* hE   = (const float*)d_in[1];
  const float* mask = (const float*)d_in[2];
  const float* fw1  = (const float*)d_in[3];
  const float* fb1  = (const float*)d_in[4];
  const float* fw2  = (const float*)d_in[5];
  const float* fb2  = (const float*)d_in[6];
  const float* hw1  = (const float*)d_in[7];
  const float* hb1  = (const float*)d_in[8];
  const float* hw2  = (const float*)d_in[9];
  const float* hb2  = (const float*)d_in[10];
  const float* hw3  = (const float*)d_in[11];
  const float* hb3  = (const float*)d_in[12];
  float* out = (float*)d_out;

  // ws: [0,64) accbuf; [64,68) ctr; fw1P @1024 (96 KB); fw2P @99328 (288 KB);
  // hEP @394240 (144 MB bf16 swizzled h_E). Total ~144.4 MB.
  float* accbuf = (float*)d_ws;
  int*   ctr    = (int*)((char*)d_ws + 64);
  unsigned short* fw1P = (unsigned short*)((char*)d_ws + 1024);
  unsigned short* fw2P = fw1P + 24 * 4 * 64 * 8;
  unsigned short* hEP  = fw2P + 24 * 12 * 64 * 8;

  const int units = Bz * Lz * NIT * KT * 16;        // 9437184
  prep_kernel<<<units / 256, 256, 0, stream>>>(fw1, fw2, hE, fw1P, fw2P, hEP,
                                               accbuf, ctr);
  schnet_main<<<Bz * Lz, 512, 0, stream>>>(hV, hEP, mask, fw1P, fb1, fw2P, fb2,
                                           hw1, hb1, hw2, hb2, hw3, hb3,
                                           accbuf, ctr, out);
}

// Round 3
// 844.299 us; speedup vs baseline: 1.0371x; 1.0371x over previous
//
#include <hip/hip_runtime.h>

// StabilityPredictorSchnet: B=4, L=384, H=128, F=384
// One block per (b,l); KT=32 edge rows per iteration, NIT=12.
// R3: (a) KT 64->32: acc[2][3]=24 regs (was 48), afr 8 (was 16) -- working
// set ~95 regs fits the (512,4) 128-reg cap; R1/R2 spilled 135-178 MB.
// (b) hEP prep dropped: main stages h_E fp32->regs (8 floats/thread, issued
// after GEMM1 mfmas; HBM latency hides under epi1+GEMM2), converts in-reg,
// ds_writes XOR-swizzled bf16 sA (swizzle both sides). Prep back to fw-only.
// LDS 32 KB. 2 barriers/iter. Swapped-mfma C^T epilogues (packed b64 sT1
// writes, float4 hV loads) retained from R2.

#define Bz 4
#define Lz 384
#define Hz 128
#define Fz 384
#define KT 32          // k-tile rows (edge rows per iteration)
#define NIT 12         // 384 / KT

typedef short bf16x8 __attribute__((ext_vector_type(8)));
typedef float f32x4 __attribute__((ext_vector_type(4)));

__device__ __forceinline__ unsigned short f2bf(float f) {
  unsigned int u = __float_as_uint(f);
  u += 0x7FFFu + ((u >> 16) & 1u);   // RNE bf16
  return (unsigned short)(u >> 16);
}

// gelu(x) = 0.5x(1+erf(x/sqrt2)); erf via A&S 7.1.26 (|err|<=1.5e-7)
__device__ __forceinline__ float gelu_f(float x) {
  const float a1 = 0.254829592f, a2 = -0.284496736f, a3 = 1.421413741f;
  const float a4 = -1.453152027f, a5 = 1.061405429f;
  float z = fabsf(x) * 0.7071067811865476f;
  float t = __builtin_amdgcn_rcpf(__builtin_fmaf(0.3275911f, z, 1.0f));
  float poly = t * (a1 + t * (a2 + t * (a3 + t * (a4 + t * a5))));
  float e = __builtin_fmaf(-poly, __expf(-z * z), 1.0f);
  return 0.5f * x * (1.0f + copysignf(e, x));
}

// ---- prep: zero acc/counter; pack fw1/fw2 into MFMA B-fragment order ----
// fw1P flat: ((t*4+ks)*64+lane)*8+j  = bf(fw1[(ks*32+(lane>>4)*8+j)*F + t*16+(lane&15)])
// fw2P flat: ((t*12+ks)*64+lane)*8+j = bf(fw2[...same...])
__global__ __launch_bounds__(256) void prep_kernel(
    const float* __restrict__ fw1, const float* __restrict__ fw2,
    unsigned short* __restrict__ fw1P, unsigned short* __restrict__ fw2P,
    float* __restrict__ accbuf, int* __restrict__ ctr)
{
  int e = blockIdx.x * 256 + threadIdx.x;
  if (e < 16) accbuf[e] = 0.0f;
  if (e == 16) *ctr = 0;
  if (e < 24 * 4 * 64 * 8) {
    int j = e & 7, lf = (e >> 3) & 63, ks = (e >> 9) & 3, t = e >> 11;
    int n = t * 16 + (lf & 15);
    int k = ks * 32 + (lf >> 4) * 8 + j;
    fw1P[e] = f2bf(fw1[(size_t)k * Fz + n]);
  } else if (e < 24 * 4 * 64 * 8 + 24 * 12 * 64 * 8) {
    int o = e - 24 * 4 * 64 * 8;
    int j = o & 7, lf = (o >> 3) & 63, r = o >> 9;
    int ks = r % 12, t = r / 12;
    int n = t * 16 + (lf & 15);
    int k = ks * 32 + (lf >> 4) * 8 + j;
    fw2P[o] = f2bf(fw2[(size_t)k * Fz + n]);
  }
}

__global__ __launch_bounds__(512, 4) void schnet_main(
    const float* __restrict__ hV, const float* __restrict__ hE,
    const float* __restrict__ mask,
    const unsigned short* __restrict__ fw1P, const float* __restrict__ fb1,
    const unsigned short* __restrict__ fw2P, const float* __restrict__ fb2,
    const float* __restrict__ hw1, const float* __restrict__ hb1,
    const float* __restrict__ hw2, const float* __restrict__ hb2,
    const float* __restrict__ hw3, const float* __restrict__ hb3,
    float* __restrict__ accbuf, int* __restrict__ ctr,
    float* __restrict__ out)
{
  const int bl   = blockIdx.x;
  const int b    = bl / Lz;
  const int l    = bl - b * Lz;
  const int tid  = threadIdx.x;
  const int wave = tid >> 6;    // 0..7
  const int lane = tid & 63;
  const int lr   = lane & 15;
  const int quad = lane >> 4;   // 0..3
  const int l7   = lane & 7;

  // 32 KB: sA bf16 swizzled tile @0 (8K), sT1 swizzled @8K (24K).
  // Head-MLP buffers alias sA after the main loop.
  __shared__ __attribute__((aligned(16))) char sMem[32768];
  unsigned short* sA  = (unsigned short*)sMem;            // [32][16 units]
  unsigned short* sT1 = (unsigned short*)(sMem + 8192);   // [32][48 units]
  float* sXC = (float*)sMem;           // 384 f
  float* sHp = sXC + Fz;               // 4*128 f  (these alias sT1 tail-safe:
  float* sH1 = sHp + 4 * Hz;           //  all loop reads are done by then)
  float* sH2 = sH1 + Hz;
  int*   sLast = (int*)(sH2 + 64);

  const float* hE_bl = hE + (size_t)bl * (Lz * Hz);
  const unsigned short* w1base = fw1P + (size_t)lane * 8;
  const unsigned short* w2base = fw2P + (size_t)lane * 8;

  // per-thread staging geometry (constant): thread owns 8 floats = 1 unit
  const int srow = tid >> 4;          // 0..31
  const int su   = tid & 15;          // unit
  const float* hE_stage = hE_bl + (size_t)tid * 8;
  unsigned short* sAw = sA + srow * 128 + (((su ^ (srow & 7)) & 15) << 3);

  const f32x4 zero4 = {0.f, 0.f, 0.f, 0.f};
  f32x4 xc[3];
  xc[0] = zero4; xc[1] = zero4; xc[2] = zero4;

  // prologue: stage tile 0 (regs -> convert -> swizzled sA)
  {
    f32x4 v0 = *(const f32x4*)hE_stage;
    f32x4 v1 = *(const f32x4*)(hE_stage + 4);
    bf16x8 o;
    o[0] = (short)f2bf(v0[0]); o[1] = (short)f2bf(v0[1]);
    o[2] = (short)f2bf(v0[2]); o[3] = (short)f2bf(v0[3]);
    o[4] = (short)f2bf(v1[0]); o[5] = (short)f2bf(v1[1]);
    o[6] = (short)f2bf(v1[2]); o[7] = (short)f2bf(v1[3]);
    *(bf16x8*)sAw = o;
  }
  __syncthreads();

  #pragma unroll 1
  for (int it = 0; it < NIT; ++it) {
    f32x4 s0, s1;

    // ===== GEMM1 (swapped mfma -> C^T): wave owns 48 cols =====
    f32x4 acc1[2][3];
    #pragma unroll
    for (int mt = 0; mt < 2; ++mt)
      #pragma unroll
      for (int nt = 0; nt < 3; ++nt) acc1[mt][nt] = zero4;

    #pragma unroll 2
    for (int ks = 0; ks < 4; ++ks) {
      const int xu = ((ks << 2) + quad) ^ l7;   // swizzled 16B-unit
      bf16x8 afr[2];
      #pragma unroll
      for (int mt = 0; mt < 2; ++mt)
        afr[mt] = *(const bf16x8*)(sA + ((mt * 16 + lr) << 7) + (xu << 3));
      bf16x8 bfr[3];
      #pragma unroll
      for (int nt = 0; nt < 3; ++nt)
        bfr[nt] = *(const bf16x8*)(w1base +
                      (size_t)(((wave * 3 + nt) * 4 + ks) * 64) * 8);
      __builtin_amdgcn_s_setprio(1);
      #pragma unroll
      for (int mt = 0; mt < 2; ++mt)
        #pragma unroll
        for (int nt = 0; nt < 3; ++nt)
          acc1[mt][nt] = __builtin_amdgcn_mfma_f32_16x16x32_bf16(
              bfr[nt], afr[mt], acc1[mt][nt], 0, 0, 0);
      __builtin_amdgcn_s_setprio(0);
    }

    // issue next-tile staging loads; latency hides under epi1 + GEMM2
    if (it + 1 < NIT) {
      const float* src = hE_stage + (size_t)(it + 1) * (KT * Hz);
      s0 = *(const f32x4*)src;
      s1 = *(const f32x4*)(src + 4);
    }

    // epi1: bias+gelu -> sT1 (swizzled write; lane holds 4 consecutive n)
    #pragma unroll
    for (int nt = 0; nt < 3; ++nt) {
      const int n0 = wave * 48 + nt * 16 + quad * 4;
      const f32x4 bias = *(const f32x4*)(fb1 + n0);
      const int so = (((wave * 6 + nt * 2 + (quad >> 1)) ^ l7) << 3)
                     + ((quad & 1) << 2);
      #pragma unroll
      for (int mt = 0; mt < 2; ++mt) {
        short4 o;
        o.x = (short)f2bf(gelu_f(acc1[mt][nt][0] + bias[0]));
        o.y = (short)f2bf(gelu_f(acc1[mt][nt][1] + bias[1]));
        o.z = (short)f2bf(gelu_f(acc1[mt][nt][2] + bias[2]));
        o.w = (short)f2bf(gelu_f(acc1[mt][nt][3] + bias[3]));
        *(short4*)(sT1 + (mt * 16 + lr) * 384 + so) = o;
      }
    }
    __syncthreads();   // sT1 ready; all sA reads (GEMM1) complete

    // ===== GEMM2 (swapped mfma -> C^T) =====
    f32x4 acc2[2][3];
    #pragma unroll
    for (int mt = 0; mt < 2; ++mt)
      #pragma unroll
      for (int nt = 0; nt < 3; ++nt) acc2[mt][nt] = zero4;

    #pragma unroll 2
    for (int ks = 0; ks < 12; ++ks) {
      const int xu = ((ks << 2) + quad) ^ l7;
      bf16x8 afr[2];
      #pragma unroll
      for (int mt = 0; mt < 2; ++mt)
        afr[mt] = *(const bf16x8*)(sT1 + (mt * 16 + lr) * 384 + (xu << 3));
      bf16x8 bfr[3];
      #pragma unroll
      for (int nt = 0; nt < 3; ++nt)
        bfr[nt] = *(const bf16x8*)(w2base +
                      (size_t)(((wave * 3 + nt) * 12 + ks) * 64) * 8);
      __builtin_amdgcn_s_setprio(1);
      #pragma unroll
      for (int mt = 0; mt < 2; ++mt)
        #pragma unroll
        for (int nt = 0; nt < 3; ++nt)
          acc2[mt][nt] = __builtin_amdgcn_mfma_f32_16x16x32_bf16(
              bfr[nt], afr[mt], acc2[mt][nt], 0, 0, 0);
      __builtin_amdgcn_s_setprio(0);
    }

    // epi2: bias+gelu, * h_V[b, k=m, n] (float4), accumulate per n
    #pragma unroll
    for (int nt = 0; nt < 3; ++nt) {
      const int n0 = wave * 48 + nt * 16 + quad * 4;
      const f32x4 b2 = *(const f32x4*)(fb2 + n0);
      #pragma unroll
      for (int mt = 0; mt < 2; ++mt) {
        const float* hv =
            hV + ((size_t)b * Lz + it * KT + mt * 16 + lr) * Fz + n0;
        const f32x4 hvv = *(const f32x4*)hv;
        #pragma unroll
        for (int r = 0; r < 4; ++r)
          xc[nt][r] += gelu_f(acc2[mt][nt][r] + b2[r]) * hvv[r];
      }
    }

    // convert staged tile -> swizzled sA (sA reads done at mid-barrier)
    if (it + 1 < NIT) {
      bf16x8 o;
      o[0] = (short)f2bf(s0[0]); o[1] = (short)f2bf(s0[1]);
      o[2] = (short)f2bf(s0[2]); o[3] = (short)f2bf(s0[3]);
      o[4] = (short)f2bf(s1[0]); o[5] = (short)f2bf(s1[1]);
      o[6] = (short)f2bf(s1[2]); o[7] = (short)f2bf(s1[3]);
      *(bf16x8*)sAw = o;
    }
    __syncthreads();   // sA ready for next GEMM1; sT1 free for next epi1
  }

  // reduce xc across the 16 lr lanes -> sXC[n] (aliases sA region, loop done)
  #pragma unroll
  for (int nt = 0; nt < 3; ++nt)
    #pragma unroll
    for (int r = 0; r < 4; ++r) {
      float v = xc[nt][r];
      v += __shfl_xor(v, 1);
      v += __shfl_xor(v, 2);
      v += __shfl_xor(v, 4);
      v += __shfl_xor(v, 8);
      if (lr == 0) sXC[wave * 48 + nt * 16 + quad * 4 + r] = v;
    }
  __syncthreads();

  // ---- head MLP (fp32, tiny) ----
  {
    int i = tid & 127;
    int part = tid >> 7;              // 0..3
    float a = 0.f;
    const int f0 = part * 96;
    for (int f = f0; f < f0 + 96; ++f) a += sXC[f] * hw1[f * Hz + i];
    sHp[part * Hz + i] = a;
  }
  __syncthreads();
  if (tid < Hz)
    sH1[tid] = gelu_f(sHp[tid] + sHp[Hz + tid] + sHp[2 * Hz + tid]
                      + sHp[3 * Hz + tid] + hb1[tid]);
  __syncthreads();
  if (tid < 64) {
    float a = hb2[tid];
    for (int i = 0; i < Hz; ++i) a += sH1[i] * hw2[i * 64 + tid];
    sH2[tid] = gelu_f(a);
  }
  __syncthreads();
  if (wave == 0) {
    float v = sH2[lane] * hw3[lane];
    #pragma unroll
    for (int off = 32; off >= 1; off >>= 1) v += __shfl_xor(v, off);
    if (lane == 0) {
      float pred = v + hb3[0];
      atomicAdd(&accbuf[b], pred * mask[b * Lz + l]);
      __threadfence();
      *sLast = (atomicAdd(ctr, 1) == (Bz * Lz - 1));
    }
  }
  __syncthreads();

  // ---- last block: finalize all 4 batches ----
  if (*sLast && wave < Bz) {
    float s = 0.f;
    #pragma unroll
    for (int k = 0; k < Lz / 64; ++k) s += mask[wave * Lz + k * 64 + lane];
    #pragma unroll
    for (int off = 32; off >= 1; off >>= 1) s += __shfl_xor(s, off);
    if (lane == 0) {
      float vl = s < 1.0f ? 1.0f : s;
      float a = atomicAdd(&accbuf[wave], 0.0f);   // coherent read
      out[wave] = a / sqrtf(vl);
    }
  }
}

extern "C" void kernel_launch(void* const* d_in, const int* in_sizes, int n_in,
                              void* d_out, int out_size, void* d_ws, size_t ws_size,
                              hipStream_t stream)
{
  const float* hV   = (const float*)d_in[0];
  const float* hE   = (const float*)d_in[1];
  const float* mask = (const float*)d_in[2];
  const float* fw1  = (const float*)d_in[3];
  const float* fb1  = (const float*)d_in[4];
  const float* fw2  = (const float*)d_in[5];
  const float* fb2  = (const float*)d_in[6];
  const float* hw1  = (const float*)d_in[7];
  const float* hb1  = (const float*)d_in[8];
  const float* hw2  = (const float*)d_in[9];
  const float* hb2  = (const float*)d_in[10];
  const float* hw3  = (const float*)d_in[11];
  const float* hb3  = (const float*)d_in[12];
  float* out = (float*)d_out;

  // ws: [0,64) accbuf; [64,68) ctr; fw1P @1024 (96 KB); fw2P after (288 KB)
  float* accbuf = (float*)d_ws;
  int*   ctr    = (int*)((char*)d_ws + 64);
  unsigned short* fw1P = (unsigned short*)((char*)d_ws + 1024);
  unsigned short* fw2P = fw1P + 24 * 4 * 64 * 8;

  prep_kernel<<<768, 256, 0, stream>>>(fw1, fw2, fw1P, fw2P, accbuf, ctr);
  schnet_main<<<Bz * Lz, 512, 0, stream>>>(hV, hE, mask, fw1P, fb1, fw2P, fb2,
                                           hw1, hb1, hw2, hb2, hw3, hb3,
                                           accbuf, ctr, out);
}